// Round 12
// baseline (228.106 us; speedup 1.0000x reference)
//
#include <hip/hip_runtime.h>

// EquiConv fused MFMA kernel for MI355X (gfx950) — round 14b (syntax fix of
// R14: '#pragma unroll' cannot follow '{' on the same line; if-chains with
// STATIC indices kept deliberately — runtime accS[wv] would scratch-allocate
// per rule #20. No functional change vs R14's design; never yet measured).
// R10+R13 falsified 3 blocks/CU (spills; VGPR bound too tight). 2 blocks/CU
// is hard. R14 attacks the two remaining geometric levers at 2 blocks/CU:
//  (1) REUSE: T=4 sub-tiles/wave (64 edges/block) -> stream bytes per edge
//      halve: 313 blocks x 1.25MB = 391MB vs R12's 780MB at the measured
//      ~9.4 TB/s depth-invariant L2 rate.
//  (2) SINGLE ROUND: 313 blocks <= 512 slots (R12 lost ~0.8xT_b to round 2).
// Register wall dodged by two-phase split at (256,2): phase A accS[4][6]
// (96 f32) -> owner-per-wave reduce -> Sfin in regs; phase B accV[4][6] fresh.
// x2 hoist moved to LDS (x2s + deinterleaved y planes); y-frags reg-hoisted.
// All 4 waves run FC/epilogue (own sub-tile). Stagger retained. LDS 76.3KB.
// Last block (312) has 32 edges: staging clamped, FC/epilogue guarded by nsub.
// prep_weights unchanged (R7).

#define E_TOT 20000

typedef __attribute__((ext_vector_type(8))) short short8;
typedef __attribute__((ext_vector_type(4))) float f32x4;
typedef __attribute__((ext_vector_type(2))) __bf16 bf16x2;

#define FRAG_USH 512
#define CH_USH   3072          // 6 frags = 6KB (stream layout unit)
#define N_CH     52
#define STRIDE_W 159744        // 312 frags * 512 ushort per wave stream
#define FC1_OFF  638976        // 4*STRIDE_W
#define FC2_OFF  647168
#define FC3_OFF  651264
#define WS_USH   657408        // 1.28 MB of d_ws

// LDS pool carve (bytes):
//   redf 24 slots x 320 f32          [0, 30720)
//   x1s  [64][66] ushort  8448       [30720, 39168)   (hb aliases here post-K)
//   x1v  [64][98] ushort 12544       [39168, 51712)
//   x2s  [64][72] ushort  9216       [51712, 60928)   (stride 144B: 16B-aligned frags)
//   y    [3][64][40] ushort 15360    [60928, 76288)   (stride 80B: 16B-aligned frags)
#define X1S_OFF  30720
#define X1V_OFF  39168
#define X2S_OFF  51712
#define Y_OFF    60928
#define POOL_B   76288

__device__ __forceinline__ unsigned short f2b(float f){
  return __builtin_bit_cast(unsigned short, (__bf16)f);
}
__device__ __forceinline__ unsigned f2b2(float lo, float hi){
  bf16x2 t; t[0] = (__bf16)lo; t[1] = (__bf16)hi;
  return __builtin_bit_cast(unsigned, t);
}
__device__ __forceinline__ float b2f(unsigned short h){
  return __uint_as_float(((unsigned)h) << 16);
}
__device__ __forceinline__ f32x4 mfma16(short8 a, short8 b, f32x4 c){
  return __builtin_amdgcn_mfma_f32_16x16x32_bf16(a, b, c, 0, 0, 0);
}
union U8 { short8 v; unsigned u[4]; };
__device__ __forceinline__ float silu_f(float x){ return x/(1.f+__expf(-x)); }
__device__ __forceinline__ float sigm_f(float x){ return 1.f/(1.f+__expf(-x)); }

// PACK8L: a = bf16(sc * b2f(frag[j])) pairs (2q, 2q+1)
#define PACK8L(a, sc, f) { \
  a.u[0]=f2b2((sc)*b2f((unsigned short)(f)[0]),(sc)*b2f((unsigned short)(f)[1])); \
  a.u[1]=f2b2((sc)*b2f((unsigned short)(f)[2]),(sc)*b2f((unsigned short)(f)[3])); \
  a.u[2]=f2b2((sc)*b2f((unsigned short)(f)[4]),(sc)*b2f((unsigned short)(f)[5])); \
  a.u[3]=f2b2((sc)*b2f((unsigned short)(f)[6]),(sc)*b2f((unsigned short)(f)[7])); }

// dest position of (k_local, n16) inside a 512-ushort fragment
__device__ __forceinline__ int fpos(int kl, int n16){
  return (kl>>3)*128 + n16*8 + (kl&7);
}

// ---------------- prep: dest-linear gather into per-wave streams ----------------
__global__ void prep_weights(const float* __restrict__ ss_s, const float* __restrict__ ss_g,
                             const float* __restrict__ vv_s, const float* __restrict__ vv_g,
                             const float* __restrict__ sv,   const float* __restrict__ vs,
                             const float* __restrict__ w1,   const float* __restrict__ w2,
                             const float* __restrict__ w3,   unsigned short* __restrict__ wsb)
{
  int g = blockIdx.x * 256 + threadIdx.x;
  if (g >= WS_USH/8) return;
  const int dest = g << 3;
  const float A_SC  = 0.013975424859373686f;                     // 1/sqrt(S*S+V*V)
  const float A_VV  = (float)(0.013975424859373686 * 0.5773502691896258);
  const float A_VEC = 0.015625f;                                 // 1/sqrt(2*S*V)

  const float* src = nullptr;
  int stride = 0;
  float scale = 1.f;

  if (dest < FC1_OFF) {                      // 4 per-wave streams
    int wave = dest / STRIDE_W;
    int off  = dest - wave*STRIDE_W;
    int c    = off / CH_USH;
    int rem  = off - c*CH_USH;
    int t    = rem >> 9;                     // fragment 0..5
    int p    = rem & 511;
    int kl   = (p >> 7) << 3;                // base kl; +j inside group
    int n16  = (p >> 3) & 15;
    if (c < 32) {                            // SS: ss_s (t0..3) + ss_g (t4,5)
      int u = (wave<<4) + (c>>1);
      int v = ((c&1)<<5) + kl;
      if (t < 4) { src = ss_s + (u<<12)+(v<<6)+((t<<4)+n16);     stride = 64; }
      else       { src = ss_g + (u<<11)+(v<<5)+(((t-4)<<4)+n16); stride = 32; }
      scale = A_SC;
    } else if (c < 40) {                     // VV: vv_s (t0..3) + vv_g (t4,5)
      int u = (wave<<3) + (c-32);
      int v = kl;
      if (t < 4) { src = vv_s + (u<<11)+(v<<6)+((t<<4)+n16);     stride = 64; }
      else       { src = vv_g + (u<<10)+(v<<5)+(((t-4)<<4)+n16); stride = 32; }
      scale = A_VV;
    } else if (c < 46) {                     // SV: chunks 40..45, ul = ch*3 + t/2
      int ul = (c-40)*3 + (t>>1);
      if (ul < 16) {
        int u = (wave<<4) + ul;
        src = sv + (u<<10)+(kl<<5)+(((t&1)<<4)+n16);
        stride = 32; scale = A_VEC;
      }                                      // else: gap frag (c=45,t>=2) -> 0
    } else {                                 // VS: chunks 46..51
      int cc = c - 46;
      int vh = cc/3, ch3 = cc - vh*3;
      int fseq = ch3*6 + t;
      if (fseq < 16) {
        int u = (wave<<3) + (fseq>>1);
        int v = (vh<<5) + kl;
        src = vs + (u<<11)+(v<<5)+(((fseq&1)<<4)+n16);
        stride = 32; scale = A_VEC;
      }                                      // else: gap frag (ch3=2,t>=4) -> 0
    }
  } else if (dest < FC2_OFF) {               // fc1 [128][64]
    int off = dest - FC1_OFF;
    int fi = off >> 9, p = off & 511;
    int kl = (p>>7)<<3, n16 = (p>>3)&15;
    int k = ((fi>>2)<<5) + kl, n = ((fi&3)<<4) + n16;
    src = w1 + (k<<6) + n; stride = 64;
  } else if (dest < FC3_OFF) {               // fc2 [64][64]
    int off = dest - FC2_OFF;
    int fi = off >> 9, p = off & 511;
    int kl = (p>>7)<<3, n16 = (p>>3)&15;
    int k = ((fi>>2)<<5) + kl, n = ((fi&3)<<4) + n16;
    src = w2 + (k<<6) + n; stride = 64;
  } else {                                   // fc3 [64][96]
    int off = dest - FC3_OFF;
    int fi = off >> 9, p = off & 511;
    int kl = (p>>7)<<3, n16 = (p>>3)&15;
    int koff = fi/6, nhi = fi - koff*6;
    int k = (koff<<5) + kl, n = (nhi<<4) + n16;
    src = w3 + k*96 + n; stride = 96;
  }

  U8 a;
  if (src) {
    float v0 = scale * src[0*stride], v1 = scale * src[1*stride];
    float v2 = scale * src[2*stride], v3 = scale * src[3*stride];
    float v4 = scale * src[4*stride], v5 = scale * src[5*stride];
    float v6 = scale * src[6*stride], v7 = scale * src[7*stride];
    a.u[0] = f2b2(v0, v1); a.u[1] = f2b2(v2, v3);
    a.u[2] = f2b2(v4, v5); a.u[3] = f2b2(v6, v7);
  } else {
    a.u[0] = 0; a.u[1] = 0; a.u[2] = 0; a.u[3] = 0;
  }
  *(short8*)(wsb + dest) = a.v;
}

// ---------------- main fused kernel ----------------
__global__ __launch_bounds__(256, 2)
void equiconv_main(const float* __restrict__ fea1,
                   const float* __restrict__ fea2,
                   const float* __restrict__ few,
                   const float* __restrict__ fb1,
                   const float* __restrict__ fb2,
                   const float* __restrict__ fb3,
                   const unsigned short* __restrict__ wsb,
                   float* __restrict__ out)
{
  __shared__ __align__(16) unsigned char pool[POOL_B];
  float*          redf = (float*)pool;
  unsigned short* x1s_ = (unsigned short*)(pool + X1S_OFF);
  unsigned short* x1v_ = (unsigned short*)(pool + X1V_OFF);
  unsigned short* x2s_ = (unsigned short*)(pool + X2S_OFF);
  unsigned short* y_   = (unsigned short*)(pool + Y_OFF);
  unsigned short* hb_  = (unsigned short*)(pool + X1S_OFF);   // alias (dead post-K)

  #define X1S(r, cc) x1s_[(r)*66 + (cc)]
  #define X1V(r, cc) x1v_[(r)*98 + (cc)]
  #define HB(w, r, cc) hb_[(((w)<<4) + (r))*72 + (cc)]

  const int tid  = threadIdx.x;
  const int lane = tid & 63, wv = tid >> 6;
  const int ln   = lane & 15, quad = lane >> 4, q8 = quad << 3;
  const int ebase = blockIdx.x << 6;          // 64 edges/block; 313 blocks
  const int nsub  = min(4, (E_TOT - ebase) >> 4);   // 4, or 2 for last block

  const int off16 = blockIdx.x & 15;
  const int off8  = blockIdx.x & 7;
  const int off6  = blockIdx.x % 6;

  // ---- stage x1 + x2 (64 edges) into LDS as bf16; clamp last-block rows ----
  for (int it = tid; it < 2560; it += 256){
    int row = it / 40, seg = it - row*40;
    int er = ebase + row; if (er > E_TOT-1) er = E_TOT-1;
    float4 v1 = *(const float4*)(fea1 + (size_t)er*160 + seg*4);
    float4 v2 = *(const float4*)(fea2 + (size_t)er*160 + seg*4);
    const float* p1 = (const float*)&v1;
    const float* p2 = (const float*)&v2;
    int c0 = seg*4;
    #pragma unroll
    for (int jj = 0; jj < 4; jj++){
      int col = c0 + jj;
      if (col < 64){
        X1S(row, col) = f2b(p1[jj]);
        x2s_[row*72 + col] = f2b(p2[jj]);
      } else {
        int vc = col - 64;
        X1V(row, vc) = f2b(p1[jj]);
        int vv = vc/3, ii = vc - vv*3;
        y_[ii*2560 + row*40 + vv] = f2b(p2[jj]);
      }
    }
  }
  __syncthreads();

  // ---- register double-buffered B-fragment stream ----
  const unsigned short* gstream = wsb + (size_t)wv*STRIDE_W + lane*8;
  auto LD = [&](int c, short8* buf){
    const unsigned short* g = gstream + c*CH_USH;
    #pragma unroll
    for (int t = 0; t < 6; t++) buf[t] = *(const short8*)(g + t*FRAG_USH);
  };

  const f32x4 z4 = {0.f,0.f,0.f,0.f};
  short8 bA[6], bB[6];
  LD(2*off16, bA);

  // =============== PHASE A: SS + VV -> accS[4][6] (96 f32) ===============
  f32x4 accS[4][6];
  #pragma unroll
  for (int s = 0; s < 4; s++)
    #pragma unroll
    for (int t = 0; t < 6; t++) accS[s][t] = z4;

  // ===== SS: pairs rotated by off16 =====
  #pragma unroll 1
  for (int i = 0; i < 16; i++){
    int p  = (i + off16) & 15;
    int pn = (i + 1 + off16) & 15;
    int u = (wv<<4) + p;
    float sc[4];
    #pragma unroll
    for (int s = 0; s < 4; s++) sc[s] = b2f(X1S(s*16+ln, u));
    {                                        // even chunk 2p (xe) from bA
      LD(2*p+1, bB);
      #pragma unroll
      for (int s = 0; s < 4; s++){
        short8 xf = *(const short8*)&x2s_[(s*16+ln)*72 + q8];
        U8 a; PACK8L(a, sc[s], xf);
        #pragma unroll
        for (int t = 0; t < 6; t++) accS[s][t] = mfma16(a.v, bA[t], accS[s][t]);
      }
    }
    {                                        // odd chunk 2p+1 (xo) from bB
      int nextc = (i < 15) ? 2*pn : (32 + off8);
      LD(nextc, bA);
      #pragma unroll
      for (int s = 0; s < 4; s++){
        short8 xf = *(const short8*)&x2s_[(s*16+ln)*72 + 32 + q8];
        U8 a; PACK8L(a, sc[s], xf);
        #pragma unroll
        for (int t = 0; t < 6; t++) accS[s][t] = mfma16(a.v, bB[t], accS[s][t]);
      }
    }
  }

  // ---- hoist y fragments (used by VV and SV) ----
  short8 y0f[4], y1f[4], y2f[4];
  #pragma unroll
  for (int s = 0; s < 4; s++){
    y0f[s] = *(const short8*)&y_[0*2560 + (s*16+ln)*40 + q8];
    y1f[s] = *(const short8*)&y_[1*2560 + (s*16+ln)*40 + q8];
    y2f[s] = *(const short8*)&y_[2*2560 + (s*16+ln)*40 + q8];
  }

  // ===== VV: 8 chunks rotated by off8 =====
  #define VVBODY(kk, buf) { \
    int u_ = (wv<<3) + (kk); \
    _Pragma("unroll") \
    for (int s = 0; s < 4; s++){ \
      float c0 = b2f(X1V(s*16+ln, u_*3+0)); \
      float c1 = b2f(X1V(s*16+ln, u_*3+1)); \
      float c2 = b2f(X1V(s*16+ln, u_*3+2)); \
      U8 a; \
      _Pragma("unroll") \
      for (int q = 0; q < 4; q++){ \
        float lo = c0*b2f((unsigned short)y0f[s][2*q])   + c1*b2f((unsigned short)y1f[s][2*q])   + c2*b2f((unsigned short)y2f[s][2*q]); \
        float hi = c0*b2f((unsigned short)y0f[s][2*q+1]) + c1*b2f((unsigned short)y1f[s][2*q+1]) + c2*b2f((unsigned short)y2f[s][2*q+1]); \
        a.u[q] = f2b2(lo, hi); \
      } \
      _Pragma("unroll") \
      for (int t = 0; t < 6; t++) accS[s][t] = mfma16(a.v, buf[t], accS[s][t]); \
    } }
  #pragma unroll 1
  for (int j = 0; j < 8; j += 2){
    int k0 = (j + off8) & 7;
    int k1 = (j + 1 + off8) & 7;
    int k2 = (j + 2 + off8) & 7;
    { LD(32+k1, bB); VVBODY(k0, bA); }
    {
      int nextc = (j < 6) ? (32 + k2) : (40 + off6);
      LD(nextc, bA);
      VVBODY(k1, bB);
    }
  }

  // ---- phase-A reduce: owner-per-wave; round r: writer w sends (w-r)&3 ----
  #define PUTS(ACC, sub) { _Pragma("unroll") for (int j=0;j<6;j++) \
    *(f32x4*)(redf + ((sub)*6+j)*320 + ln*20 + (quad<<2)) = ACC[sub][j]; }
  #define ADDS(ACC, o)   { _Pragma("unroll") for (int j=0;j<6;j++) \
    ACC[o][j] += *(const f32x4*)(redf + ((o)*6+j)*320 + ln*20 + (quad<<2)); }
  #define REDUCE4(ACC) { \
    if (wv==0) PUTS(ACC,3) if (wv==1) PUTS(ACC,0) if (wv==2) PUTS(ACC,1) if (wv==3) PUTS(ACC,2) \
    __syncthreads(); \
    if (wv==0) ADDS(ACC,0) if (wv==1) ADDS(ACC,1) if (wv==2) ADDS(ACC,2) if (wv==3) ADDS(ACC,3) \
    __syncthreads(); \
    if (wv==0) PUTS(ACC,2) if (wv==1) PUTS(ACC,3) if (wv==2) PUTS(ACC,0) if (wv==3) PUTS(ACC,1) \
    __syncthreads(); \
    if (wv==0) ADDS(ACC,0) if (wv==1) ADDS(ACC,1) if (wv==2) ADDS(ACC,2) if (wv==3) ADDS(ACC,3) \
    __syncthreads(); \
    if (wv==0) PUTS(ACC,1) if (wv==1) PUTS(ACC,2) if (wv==2) PUTS(ACC,3) if (wv==3) PUTS(ACC,0) \
    __syncthreads(); \
    if (wv==0) ADDS(ACC,0) if (wv==1) ADDS(ACC,1) if (wv==2) ADDS(ACC,2) if (wv==3) ADDS(ACC,3) }

  __syncthreads();
  REDUCE4(accS);
  // wave w now owns final S-tiles of sub-tile w in accS[w]
  f32x4 Sfin[6];
  if (wv==0){
    #pragma unroll
    for (int j=0;j<6;j++) Sfin[j]=accS[0][j];
  }
  if (wv==1){
    #pragma unroll
    for (int j=0;j<6;j++) Sfin[j]=accS[1][j];
  }
  if (wv==2){
    #pragma unroll
    for (int j=0;j<6;j++) Sfin[j]=accS[2][j];
  }
  if (wv==3){
    #pragma unroll
    for (int j=0;j<6;j++) Sfin[j]=accS[3][j];
  }
  __syncthreads();                 // slots free for phase-B reduce

  // =============== PHASE B: SV + VS -> accV[4][6] (96 f32) ===============
  f32x4 accV[4][6];
  #pragma unroll
  for (int s = 0; s < 4; s++)
    #pragma unroll
    for (int t = 0; t < 6; t++) accV[s][t] = z4;

  // ===== SV: 6 chunks rotated by off6; acc index j = t*3 + i =====
  #define SVBODY(chv, buf) { \
    _Pragma("unroll") \
    for (int uu = 0; uu < 3; uu++){ \
      int ui = (chv)*3 + uu; \
      if (ui < 16){ \
        int u_ = (wv<<4) + ui; \
        _Pragma("unroll") \
        for (int s = 0; s < 4; s++){ \
          float scs = b2f(X1S(s*16+ln, u_)); \
          U8 a0, a1, a2; \
          PACK8L(a0, scs, y0f[s]); PACK8L(a1, scs, y1f[s]); PACK8L(a2, scs, y2f[s]); \
          _Pragma("unroll") \
          for (int t = 0; t < 2; t++){ \
            short8 b8 = buf[uu*2 + t]; \
            accV[s][t*3+0] = mfma16(a0.v, b8, accV[s][t*3+0]); \
            accV[s][t*3+1] = mfma16(a1.v, b8, accV[s][t*3+1]); \
            accV[s][t*3+2] = mfma16(a2.v, b8, accV[s][t*3+2]); \
          } \
        } \
      } \
    } }
  #pragma unroll 1
  for (int j = 0; j < 6; j += 2){
    int c0i = j + off6;     if (c0i >= 6) c0i -= 6;
    int c1i = j + 1 + off6; if (c1i >= 6) c1i -= 6;
    int c2i = j + 2 + off6; if (c2i >= 6) c2i -= 6;
    { LD(40 + c1i, bB); SVBODY(c0i, bA); }
    {
      int nextc = (j < 4) ? (40 + c2i) : (46 + off6);
      LD(nextc, bA);
      SVBODY(c1i, bB);
    }
  }
  // ===== VS: 6 chunks rotated by off6 =====
  #define VSBODY(pcv, buf) { \
    const int p_ = (pcv)/3, ch_ = (pcv) - p_*3; \
    _Pragma("unroll") \
    for (int uu = 0; uu < 3; uu++){ \
      int ui = ch_*3 + uu; \
      if (ui < 8){ \
        int u_ = (wv<<3) + ui; \
        _Pragma("unroll") \
        for (int s = 0; s < 4; s++){ \
          float c0 = b2f(X1V(s*16+ln, u_*3+0)); \
          float c1 = b2f(X1V(s*16+ln, u_*3+1)); \
          float c2 = b2f(X1V(s*16+ln, u_*3+2)); \
          short8 xf = *(const short8*)&x2s_[(s*16+ln)*72 + p_*32 + q8]; \
          U8 a0, a1, a2; \
          PACK8L(a0, c0, xf); PACK8L(a1, c1, xf); PACK8L(a2, c2, xf); \
          _Pragma("unroll") \
          for (int t = 0; t < 2; t++){ \
            short8 b8 = buf[uu*2 + t]; \
            accV[s][t*3+0] = mfma16(a0.v, b8, accV[s][t*3+0]); \
            accV[s][t*3+1] = mfma16(a1.v, b8, accV[s][t*3+1]); \
            accV[s][t*3+2] = mfma16(a2.v, b8, accV[s][t*3+2]); \
          } \
        } \
      } \
    } }
  #pragma unroll 1
  for (int j = 0; j < 6; j += 2){
    int c0i = j + off6;     if (c0i >= 6) c0i -= 6;
    int c1i = j + 1 + off6; if (c1i >= 6) c1i -= 6;
    int c2i = j + 2 + off6; if (c2i >= 6) c2i -= 6;
    { LD(46 + c1i, bB); VSBODY(c0i, bA); }
    {
      if (j < 4) LD(46 + c2i, bA);
      VSBODY(c1i, bB);
    }
  }

  // ---- phase-B reduce ----
  REDUCE4(accV);
  f32x4 Vfin[6];
  if (wv==0){
    #pragma unroll
    for (int j=0;j<6;j++) Vfin[j]=accV[0][j];
  }
  if (wv==1){
    #pragma unroll
    for (int j=0;j<6;j++) Vfin[j]=accV[1][j];
  }
  if (wv==2){
    #pragma unroll
    for (int j=0;j<6;j++) Vfin[j]=accV[2][j];
  }
  if (wv==3){
    #pragma unroll
    for (int j=0;j<6;j++) Vfin[j]=accV[3][j];
  }

  if (wv >= nsub) return;

  // ---- P[12]: S-tiles then V-tiles ----
  f32x4 P[12];
  #pragma unroll
  for (int j = 0; j < 6; j++){ P[j] = Sfin[j]; P[6+j] = Vfin[j]; }

  // ---- FC chain (each wave: own sub-tile wv; wave-private hb) ----
  f32x4 accF[4] = {z4,z4,z4,z4};
  {
    const float* fwp = few + (size_t)(ebase + wv*16 + ln)*128;
    const short8* B = (const short8*)(wsb + FC1_OFF);
    #pragma unroll
    for (int c = 0; c < 4; c++){
      float4 fa  = *(const float4*)(fwp + c*32 + q8);
      float4 fbv = *(const float4*)(fwp + c*32 + q8 + 4);
      U8 a;
      a.u[0]=f2b2(fa.x,fa.y);   a.u[1]=f2b2(fa.z,fa.w);
      a.u[2]=f2b2(fbv.x,fbv.y); a.u[3]=f2b2(fbv.z,fbv.w);
      #pragma unroll
      for (int t = 0; t < 4; t++) accF[t] = mfma16(a.v, B[(c*4+t)*64 + lane], accF[t]);
    }
  }
  #pragma unroll
  for (int t = 0; t < 4; t++){
    float bb = fb1[(t<<4)+ln];
    #pragma unroll
    for (int r = 0; r < 4; r++)
      HB(wv, (quad<<2)+r, (t<<4)+ln) = f2b(silu_f(accF[t][r] + bb));
  }
  f32x4 acc2[4] = {z4,z4,z4,z4};
  {
    const short8* B = (const short8*)(wsb + FC2_OFF);
    #pragma unroll
    for (int c = 0; c < 2; c++){
      uint4 hq = *(const uint4*)&HB(wv, ln, c*32 + q8);
      U8 a; a.u[0]=hq.x; a.u[1]=hq.y; a.u[2]=hq.z; a.u[3]=hq.w;
      #pragma unroll
      for (int t = 0; t < 4; t++) acc2[t] = mfma16(a.v, B[(c*4+t)*64 + lane], acc2[t]);
    }
  }
  #pragma unroll
  for (int t = 0; t < 4; t++){
    float bb = fb2[(t<<4)+ln];
    #pragma unroll
    for (int r = 0; r < 4; r++)
      HB(wv, (quad<<2)+r, (t<<4)+ln) = f2b(silu_f(acc2[t][r] + bb));
  }
  f32x4 acc3[6] = {z4,z4,z4,z4,z4,z4};
  {
    const short8* B = (const short8*)(wsb + FC3_OFF);
    #pragma unroll
    for (int c = 0; c < 2; c++){
      uint4 hq = *(const uint4*)&HB(wv, ln, c*32 + q8);
      U8 a; a.u[0]=hq.x; a.u[1]=hq.y; a.u[2]=hq.z; a.u[3]=hq.w;
      #pragma unroll
      for (int t = 0; t < 6; t++) acc3[t] = mfma16(a.v, B[(c*6+t)*64 + lane], acc3[t]);
    }
  }

  // ---- epilogue ----
  #pragma unroll
  for (int r = 0; r < 4; r++){
    int eg = ebase + wv*16 + (quad<<2) + r;
    float* op = out + (size_t)eg*160;
    #pragma unroll
    for (int t = 0; t < 4; t++)
      op[(t<<4)+ln] = silu_f(P[t][r]) * (acc3[t][r] + fb3[(t<<4)+ln]);
    #pragma unroll
    for (int tp = 0; tp < 2; tp++){
      int wc = (tp<<4) + ln;
      float f = sigm_f(P[4+tp][r]) * (acc3[4+tp][r] + fb3[64+wc]);
      op[64 + wc*3 + 0] = P[6+3*tp+0][r] * f;
      op[64 + wc*3 + 1] = P[6+3*tp+1][r] * f;
      op[64 + wc*3 + 2] = P[6+3*tp+2][r] * f;
    }
  }
}

extern "C" void kernel_launch(void* const* d_in, const int* in_sizes, int n_in,
                              void* d_out, int out_size, void* d_ws, size_t ws_size,
                              hipStream_t stream) {
  (void)in_sizes; (void)n_in; (void)out_size; (void)ws_size;
  unsigned short* wsb = (unsigned short*)d_ws;

  prep_weights<<<(WS_USH/8 + 255)/256, 256, 0, stream>>>(
      (const float*)d_in[3], (const float*)d_in[5],     // ss_s, ss_g
      (const float*)d_in[4], (const float*)d_in[6],     // vv_s, vv_g
      (const float*)d_in[7], (const float*)d_in[8],     // sv, vs
      (const float*)d_in[9], (const float*)d_in[11], (const float*)d_in[13],
      wsb);

  equiconv_main<<<(E_TOT + 63)/64, 256, 0, stream>>>(
      (const float*)d_in[0], (const float*)d_in[1], (const float*)d_in[2],
      (const float*)d_in[10], (const float*)d_in[12], (const float*)d_in[14],
      (const unsigned short*)wsb, (float*)d_out);
}

// Round 13
// 194.700 us; speedup vs baseline: 1.1716x; 1.1716x over previous
//
#include <hip/hip_runtime.h>

// EquiConv fused MFMA kernel for MI355X (gfx950) — round 15 (lean T=4).
// R14b passed (mapping correct, absmax 0.03125) but spilled: WRITE 12.5->60.6MB
// scratch; live set ~290 (accS 96 + y-hoist 48 + dbuf 48 + Sfin 24 + temps) over
// the 256 unified budget at 2 waves/SIMD. R8's scaling (per-block time doubles
// when waves/CU halve) pins the binder as a per-CU memory-return cap ~16B/cy ->
// T=4's traffic halving (391MB vs 780MB) is the right lever IF it fits.
// R15 = R14b minus the 48-reg y-fragment hoist (read y planes from LDS per use,
// transient; 2-way conflicts only). Everything else identical: dbuf bA/bB,
// two-phase accS->accV, owner-per-wave reduce, static Sfin/Vfin if-chains,
// stagger, (256,2), 313 blocks single round. Live ~240 < 256.
// Same values & accumulation order -> absmax canary 0.03125.
// Spill canary: WRITE > 14MB -> revert to R12. prep_weights unchanged (R7).

#define E_TOT 20000

typedef __attribute__((ext_vector_type(8))) short short8;
typedef __attribute__((ext_vector_type(4))) float f32x4;
typedef __attribute__((ext_vector_type(2))) __bf16 bf16x2;

#define FRAG_USH 512
#define CH_USH   3072          // 6 frags = 6KB (stream layout unit)
#define N_CH     52
#define STRIDE_W 159744        // 312 frags * 512 ushort per wave stream
#define FC1_OFF  638976        // 4*STRIDE_W
#define FC2_OFF  647168
#define FC3_OFF  651264
#define WS_USH   657408        // 1.28 MB of d_ws

// LDS pool carve (bytes):
//   redf 24 slots x 320 f32          [0, 30720)
//   x1s  [64][66] ushort  8448       [30720, 39168)   (hb aliases here post-K)
//   x1v  [64][98] ushort 12544       [39168, 51712)
//   x2s  [64][72] ushort  9216       [51712, 60928)   (stride 144B)
//   y    [3][64][40] ushort 15360    [60928, 76288)   (stride 80B)
#define X1S_OFF  30720
#define X1V_OFF  39168
#define X2S_OFF  51712
#define Y_OFF    60928
#define POOL_B   76288

__device__ __forceinline__ unsigned short f2b(float f){
  return __builtin_bit_cast(unsigned short, (__bf16)f);
}
__device__ __forceinline__ unsigned f2b2(float lo, float hi){
  bf16x2 t; t[0] = (__bf16)lo; t[1] = (__bf16)hi;
  return __builtin_bit_cast(unsigned, t);
}
__device__ __forceinline__ float b2f(unsigned short h){
  return __uint_as_float(((unsigned)h) << 16);
}
__device__ __forceinline__ f32x4 mfma16(short8 a, short8 b, f32x4 c){
  return __builtin_amdgcn_mfma_f32_16x16x32_bf16(a, b, c, 0, 0, 0);
}
union U8 { short8 v; unsigned u[4]; };
__device__ __forceinline__ float silu_f(float x){ return x/(1.f+__expf(-x)); }
__device__ __forceinline__ float sigm_f(float x){ return 1.f/(1.f+__expf(-x)); }

// PACK8L: a = bf16(sc * b2f(frag[j])) pairs (2q, 2q+1)
#define PACK8L(a, sc, f) { \
  a.u[0]=f2b2((sc)*b2f((unsigned short)(f)[0]),(sc)*b2f((unsigned short)(f)[1])); \
  a.u[1]=f2b2((sc)*b2f((unsigned short)(f)[2]),(sc)*b2f((unsigned short)(f)[3])); \
  a.u[2]=f2b2((sc)*b2f((unsigned short)(f)[4]),(sc)*b2f((unsigned short)(f)[5])); \
  a.u[3]=f2b2((sc)*b2f((unsigned short)(f)[6]),(sc)*b2f((unsigned short)(f)[7])); }

// dest position of (k_local, n16) inside a 512-ushort fragment
__device__ __forceinline__ int fpos(int kl, int n16){
  return (kl>>3)*128 + n16*8 + (kl&7);
}

// ---------------- prep: dest-linear gather into per-wave streams ----------------
__global__ void prep_weights(const float* __restrict__ ss_s, const float* __restrict__ ss_g,
                             const float* __restrict__ vv_s, const float* __restrict__ vv_g,
                             const float* __restrict__ sv,   const float* __restrict__ vs,
                             const float* __restrict__ w1,   const float* __restrict__ w2,
                             const float* __restrict__ w3,   unsigned short* __restrict__ wsb)
{
  int g = blockIdx.x * 256 + threadIdx.x;
  if (g >= WS_USH/8) return;
  const int dest = g << 3;
  const float A_SC  = 0.013975424859373686f;                     // 1/sqrt(S*S+V*V)
  const float A_VV  = (float)(0.013975424859373686 * 0.5773502691896258);
  const float A_VEC = 0.015625f;                                 // 1/sqrt(2*S*V)

  const float* src = nullptr;
  int stride = 0;
  float scale = 1.f;

  if (dest < FC1_OFF) {                      // 4 per-wave streams
    int wave = dest / STRIDE_W;
    int off  = dest - wave*STRIDE_W;
    int c    = off / CH_USH;
    int rem  = off - c*CH_USH;
    int t    = rem >> 9;                     // fragment 0..5
    int p    = rem & 511;
    int kl   = (p >> 7) << 3;                // base kl; +j inside group
    int n16  = (p >> 3) & 15;
    if (c < 32) {                            // SS: ss_s (t0..3) + ss_g (t4,5)
      int u = (wave<<4) + (c>>1);
      int v = ((c&1)<<5) + kl;
      if (t < 4) { src = ss_s + (u<<12)+(v<<6)+((t<<4)+n16);     stride = 64; }
      else       { src = ss_g + (u<<11)+(v<<5)+(((t-4)<<4)+n16); stride = 32; }
      scale = A_SC;
    } else if (c < 40) {                     // VV: vv_s (t0..3) + vv_g (t4,5)
      int u = (wave<<3) + (c-32);
      int v = kl;
      if (t < 4) { src = vv_s + (u<<11)+(v<<6)+((t<<4)+n16);     stride = 64; }
      else       { src = vv_g + (u<<10)+(v<<5)+(((t-4)<<4)+n16); stride = 32; }
      scale = A_VV;
    } else if (c < 46) {                     // SV: chunks 40..45, ul = ch*3 + t/2
      int ul = (c-40)*3 + (t>>1);
      if (ul < 16) {
        int u = (wave<<4) + ul;
        src = sv + (u<<10)+(kl<<5)+(((t&1)<<4)+n16);
        stride = 32; scale = A_VEC;
      }                                      // else: gap frag (c=45,t>=2) -> 0
    } else {                                 // VS: chunks 46..51
      int cc = c - 46;
      int vh = cc/3, ch3 = cc - vh*3;
      int fseq = ch3*6 + t;
      if (fseq < 16) {
        int u = (wave<<3) + (fseq>>1);
        int v = (vh<<5) + kl;
        src = vs + (u<<11)+(v<<5)+(((fseq&1)<<4)+n16);
        stride = 32; scale = A_VEC;
      }                                      // else: gap frag (ch3=2,t>=4) -> 0
    }
  } else if (dest < FC2_OFF) {               // fc1 [128][64]
    int off = dest - FC1_OFF;
    int fi = off >> 9, p = off & 511;
    int kl = (p>>7)<<3, n16 = (p>>3)&15;
    int k = ((fi>>2)<<5) + kl, n = ((fi&3)<<4) + n16;
    src = w1 + (k<<6) + n; stride = 64;
  } else if (dest < FC3_OFF) {               // fc2 [64][64]
    int off = dest - FC2_OFF;
    int fi = off >> 9, p = off & 511;
    int kl = (p>>7)<<3, n16 = (p>>3)&15;
    int k = ((fi>>2)<<5) + kl, n = ((fi&3)<<4) + n16;
    src = w2 + (k<<6) + n; stride = 64;
  } else {                                   // fc3 [64][96]
    int off = dest - FC3_OFF;
    int fi = off >> 9, p = off & 511;
    int kl = (p>>7)<<3, n16 = (p>>3)&15;
    int koff = fi/6, nhi = fi - koff*6;
    int k = (koff<<5) + kl, n = (nhi<<4) + n16;
    src = w3 + k*96 + n; stride = 96;
  }

  U8 a;
  if (src) {
    float v0 = scale * src[0*stride], v1 = scale * src[1*stride];
    float v2 = scale * src[2*stride], v3 = scale * src[3*stride];
    float v4 = scale * src[4*stride], v5 = scale * src[5*stride];
    float v6 = scale * src[6*stride], v7 = scale * src[7*stride];
    a.u[0] = f2b2(v0, v1); a.u[1] = f2b2(v2, v3);
    a.u[2] = f2b2(v4, v5); a.u[3] = f2b2(v6, v7);
  } else {
    a.u[0] = 0; a.u[1] = 0; a.u[2] = 0; a.u[3] = 0;
  }
  *(short8*)(wsb + dest) = a.v;
}

// ---------------- main fused kernel ----------------
__global__ __launch_bounds__(256, 2)
void equiconv_main(const float* __restrict__ fea1,
                   const float* __restrict__ fea2,
                   const float* __restrict__ few,
                   const float* __restrict__ fb1,
                   const float* __restrict__ fb2,
                   const float* __restrict__ fb3,
                   const unsigned short* __restrict__ wsb,
                   float* __restrict__ out)
{
  __shared__ __align__(16) unsigned char pool[POOL_B];
  float*          redf = (float*)pool;
  unsigned short* x1s_ = (unsigned short*)(pool + X1S_OFF);
  unsigned short* x1v_ = (unsigned short*)(pool + X1V_OFF);
  unsigned short* x2s_ = (unsigned short*)(pool + X2S_OFF);
  unsigned short* y_   = (unsigned short*)(pool + Y_OFF);
  unsigned short* hb_  = (unsigned short*)(pool + X1S_OFF);   // alias (dead post-K)

  #define X1S(r, cc) x1s_[(r)*66 + (cc)]
  #define X1V(r, cc) x1v_[(r)*98 + (cc)]
  #define HB(w, r, cc) hb_[(((w)<<4) + (r))*72 + (cc)]

  const int tid  = threadIdx.x;
  const int lane = tid & 63, wv = tid >> 6;
  const int ln   = lane & 15, quad = lane >> 4, q8 = quad << 3;
  const int ebase = blockIdx.x << 6;          // 64 edges/block; 313 blocks
  const int nsub  = min(4, (E_TOT - ebase) >> 4);   // 4, or 2 for last block

  const int off16 = blockIdx.x & 15;
  const int off8  = blockIdx.x & 7;
  const int off6  = blockIdx.x % 6;

  // ---- stage x1 + x2 (64 edges) into LDS as bf16; clamp last-block rows ----
  for (int it = tid; it < 2560; it += 256){
    int row = it / 40, seg = it - row*40;
    int er = ebase + row; if (er > E_TOT-1) er = E_TOT-1;
    float4 v1 = *(const float4*)(fea1 + (size_t)er*160 + seg*4);
    float4 v2 = *(const float4*)(fea2 + (size_t)er*160 + seg*4);
    const float* p1 = (const float*)&v1;
    const float* p2 = (const float*)&v2;
    int c0 = seg*4;
    #pragma unroll
    for (int jj = 0; jj < 4; jj++){
      int col = c0 + jj;
      if (col < 64){
        X1S(row, col) = f2b(p1[jj]);
        x2s_[row*72 + col] = f2b(p2[jj]);
      } else {
        int vc = col - 64;
        X1V(row, vc) = f2b(p1[jj]);
        int vv = vc/3, ii = vc - vv*3;
        y_[ii*2560 + row*40 + vv] = f2b(p2[jj]);
      }
    }
  }
  __syncthreads();

  // ---- register double-buffered B-fragment stream ----
  const unsigned short* gstream = wsb + (size_t)wv*STRIDE_W + lane*8;
  auto LD = [&](int c, short8* buf){
    const unsigned short* g = gstream + c*CH_USH;
    #pragma unroll
    for (int t = 0; t < 6; t++) buf[t] = *(const short8*)(g + t*FRAG_USH);
  };

  const f32x4 z4 = {0.f,0.f,0.f,0.f};
  short8 bA[6], bB[6];
  LD(2*off16, bA);

  // =============== PHASE A: SS + VV -> accS[4][6] (96 f32) ===============
  f32x4 accS[4][6];
  #pragma unroll
  for (int s = 0; s < 4; s++)
    #pragma unroll
    for (int t = 0; t < 6; t++) accS[s][t] = z4;

  // ===== SS: pairs rotated by off16 =====
  #pragma unroll 1
  for (int i = 0; i < 16; i++){
    int p  = (i + off16) & 15;
    int pn = (i + 1 + off16) & 15;
    int u = (wv<<4) + p;
    float sc[4];
    #pragma unroll
    for (int s = 0; s < 4; s++) sc[s] = b2f(X1S(s*16+ln, u));
    {                                        // even chunk 2p (xe) from bA
      LD(2*p+1, bB);
      #pragma unroll
      for (int s = 0; s < 4; s++){
        short8 xf = *(const short8*)&x2s_[(s*16+ln)*72 + q8];
        U8 a; PACK8L(a, sc[s], xf);
        #pragma unroll
        for (int t = 0; t < 6; t++) accS[s][t] = mfma16(a.v, bA[t], accS[s][t]);
      }
    }
    {                                        // odd chunk 2p+1 (xo) from bB
      int nextc = (i < 15) ? 2*pn : (32 + off8);
      LD(nextc, bA);
      #pragma unroll
      for (int s = 0; s < 4; s++){
        short8 xf = *(const short8*)&x2s_[(s*16+ln)*72 + 32 + q8];
        U8 a; PACK8L(a, sc[s], xf);
        #pragma unroll
        for (int t = 0; t < 6; t++) accS[s][t] = mfma16(a.v, bB[t], accS[s][t]);
      }
    }
  }

  // ===== VV: 8 chunks rotated by off8; y planes read from LDS per use =====
  #define VVBODY(kk, buf) { \
    int u_ = (wv<<3) + (kk); \
    _Pragma("unroll") \
    for (int s = 0; s < 4; s++){ \
      float c0 = b2f(X1V(s*16+ln, u_*3+0)); \
      float c1 = b2f(X1V(s*16+ln, u_*3+1)); \
      float c2 = b2f(X1V(s*16+ln, u_*3+2)); \
      short8 y0 = *(const short8*)&y_[(s*16+ln)*40 + q8]; \
      short8 y1 = *(const short8*)&y_[2560 + (s*16+ln)*40 + q8]; \
      short8 y2 = *(const short8*)&y_[5120 + (s*16+ln)*40 + q8]; \
      U8 a; \
      _Pragma("unroll") \
      for (int q = 0; q < 4; q++){ \
        float lo = c0*b2f((unsigned short)y0[2*q])   + c1*b2f((unsigned short)y1[2*q])   + c2*b2f((unsigned short)y2[2*q]); \
        float hi = c0*b2f((unsigned short)y0[2*q+1]) + c1*b2f((unsigned short)y1[2*q+1]) + c2*b2f((unsigned short)y2[2*q+1]); \
        a.u[q] = f2b2(lo, hi); \
      } \
      _Pragma("unroll") \
      for (int t = 0; t < 6; t++) accS[s][t] = mfma16(a.v, buf[t], accS[s][t]); \
    } }
  #pragma unroll 1
  for (int j = 0; j < 8; j += 2){
    int k0 = (j + off8) & 7;
    int k1 = (j + 1 + off8) & 7;
    int k2 = (j + 2 + off8) & 7;
    { LD(32+k1, bB); VVBODY(k0, bA); }
    {
      int nextc = (j < 6) ? (32 + k2) : (40 + off6);
      LD(nextc, bA);
      VVBODY(k1, bB);
    }
  }

  // ---- phase-A reduce: owner-per-wave; round r: writer w sends (w-r)&3 ----
  #define PUTS(ACC, sub) { _Pragma("unroll") for (int j=0;j<6;j++) \
    *(f32x4*)(redf + ((sub)*6+j)*320 + ln*20 + (quad<<2)) = ACC[sub][j]; }
  #define ADDS(ACC, o)   { _Pragma("unroll") for (int j=0;j<6;j++) \
    ACC[o][j] += *(const f32x4*)(redf + ((o)*6+j)*320 + ln*20 + (quad<<2)); }
  #define REDUCE4(ACC) { \
    if (wv==0) PUTS(ACC,3) if (wv==1) PUTS(ACC,0) if (wv==2) PUTS(ACC,1) if (wv==3) PUTS(ACC,2) \
    __syncthreads(); \
    if (wv==0) ADDS(ACC,0) if (wv==1) ADDS(ACC,1) if (wv==2) ADDS(ACC,2) if (wv==3) ADDS(ACC,3) \
    __syncthreads(); \
    if (wv==0) PUTS(ACC,2) if (wv==1) PUTS(ACC,3) if (wv==2) PUTS(ACC,0) if (wv==3) PUTS(ACC,1) \
    __syncthreads(); \
    if (wv==0) ADDS(ACC,0) if (wv==1) ADDS(ACC,1) if (wv==2) ADDS(ACC,2) if (wv==3) ADDS(ACC,3) \
    __syncthreads(); \
    if (wv==0) PUTS(ACC,1) if (wv==1) PUTS(ACC,2) if (wv==2) PUTS(ACC,3) if (wv==3) PUTS(ACC,0) \
    __syncthreads(); \
    if (wv==0) ADDS(ACC,0) if (wv==1) ADDS(ACC,1) if (wv==2) ADDS(ACC,2) if (wv==3) ADDS(ACC,3) }

  __syncthreads();
  REDUCE4(accS);
  // wave w now owns final S-tiles of sub-tile w in accS[w]
  f32x4 Sfin[6];
  if (wv==0){
    #pragma unroll
    for (int j=0;j<6;j++) Sfin[j]=accS[0][j];
  }
  if (wv==1){
    #pragma unroll
    for (int j=0;j<6;j++) Sfin[j]=accS[1][j];
  }
  if (wv==2){
    #pragma unroll
    for (int j=0;j<6;j++) Sfin[j]=accS[2][j];
  }
  if (wv==3){
    #pragma unroll
    for (int j=0;j<6;j++) Sfin[j]=accS[3][j];
  }
  __syncthreads();                 // slots free for phase-B reduce

  // =============== PHASE B: SV + VS -> accV[4][6] (96 f32) ===============
  f32x4 accV[4][6];
  #pragma unroll
  for (int s = 0; s < 4; s++)
    #pragma unroll
    for (int t = 0; t < 6; t++) accV[s][t] = z4;

  // ===== SV: 6 chunks rotated by off6; y planes from LDS per use =====
  #define SVBODY(chv, buf) { \
    _Pragma("unroll") \
    for (int uu = 0; uu < 3; uu++){ \
      int ui = (chv)*3 + uu; \
      if (ui < 16){ \
        int u_ = (wv<<4) + ui; \
        _Pragma("unroll") \
        for (int s = 0; s < 4; s++){ \
          float scs = b2f(X1S(s*16+ln, u_)); \
          short8 y0 = *(const short8*)&y_[(s*16+ln)*40 + q8]; \
          short8 y1 = *(const short8*)&y_[2560 + (s*16+ln)*40 + q8]; \
          short8 y2 = *(const short8*)&y_[5120 + (s*16+ln)*40 + q8]; \
          U8 a0, a1, a2; \
          PACK8L(a0, scs, y0); PACK8L(a1, scs, y1); PACK8L(a2, scs, y2); \
          _Pragma("unroll") \
          for (int t = 0; t < 2; t++){ \
            short8 b8 = buf[uu*2 + t]; \
            accV[s][t*3+0] = mfma16(a0.v, b8, accV[s][t*3+0]); \
            accV[s][t*3+1] = mfma16(a1.v, b8, accV[s][t*3+1]); \
            accV[s][t*3+2] = mfma16(a2.v, b8, accV[s][t*3+2]); \
          } \
        } \
      } \
    } }
  #pragma unroll 1
  for (int j = 0; j < 6; j += 2){
    int c0i = j + off6;     if (c0i >= 6) c0i -= 6;
    int c1i = j + 1 + off6; if (c1i >= 6) c1i -= 6;
    int c2i = j + 2 + off6; if (c2i >= 6) c2i -= 6;
    { LD(40 + c1i, bB); SVBODY(c0i, bA); }
    {
      int nextc = (j < 4) ? (40 + c2i) : (46 + off6);
      LD(nextc, bA);
      SVBODY(c1i, bB);
    }
  }
  // ===== VS: 6 chunks rotated by off6 =====
  #define VSBODY(pcv, buf) { \
    const int p_ = (pcv)/3, ch_ = (pcv) - p_*3; \
    _Pragma("unroll") \
    for (int uu = 0; uu < 3; uu++){ \
      int ui = ch_*3 + uu; \
      if (ui < 8){ \
        int u_ = (wv<<3) + ui; \
        _Pragma("unroll") \
        for (int s = 0; s < 4; s++){ \
          float c0 = b2f(X1V(s*16+ln, u_*3+0)); \
          float c1 = b2f(X1V(s*16+ln, u_*3+1)); \
          float c2 = b2f(X1V(s*16+ln, u_*3+2)); \
          short8 xf = *(const short8*)&x2s_[(s*16+ln)*72 + p_*32 + q8]; \
          U8 a0, a1, a2; \
          PACK8L(a0, c0, xf); PACK8L(a1, c1, xf); PACK8L(a2, c2, xf); \
          _Pragma("unroll") \
          for (int t = 0; t < 2; t++){ \
            short8 b8 = buf[uu*2 + t]; \
            accV[s][t*3+0] = mfma16(a0.v, b8, accV[s][t*3+0]); \
            accV[s][t*3+1] = mfma16(a1.v, b8, accV[s][t*3+1]); \
            accV[s][t*3+2] = mfma16(a2.v, b8, accV[s][t*3+2]); \
          } \
        } \
      } \
    } }
  #pragma unroll 1
  for (int j = 0; j < 6; j += 2){
    int c0i = j + off6;     if (c0i >= 6) c0i -= 6;
    int c1i = j + 1 + off6; if (c1i >= 6) c1i -= 6;
    int c2i = j + 2 + off6; if (c2i >= 6) c2i -= 6;
    { LD(46 + c1i, bB); VSBODY(c0i, bA); }
    {
      if (j < 4) LD(46 + c2i, bA);
      VSBODY(c1i, bB);
    }
  }

  // ---- phase-B reduce ----
  REDUCE4(accV);
  f32x4 Vfin[6];
  if (wv==0){
    #pragma unroll
    for (int j=0;j<6;j++) Vfin[j]=accV[0][j];
  }
  if (wv==1){
    #pragma unroll
    for (int j=0;j<6;j++) Vfin[j]=accV[1][j];
  }
  if (wv==2){
    #pragma unroll
    for (int j=0;j<6;j++) Vfin[j]=accV[2][j];
  }
  if (wv==3){
    #pragma unroll
    for (int j=0;j<6;j++) Vfin[j]=accV[3][j];
  }

  if (wv >= nsub) return;

  // ---- P[12]: S-tiles then V-tiles ----
  f32x4 P[12];
  #pragma unroll
  for (int j = 0; j < 6; j++){ P[j] = Sfin[j]; P[6+j] = Vfin[j]; }

  // ---- FC chain (each wave: own sub-tile wv; wave-private hb) ----
  f32x4 accF[4] = {z4,z4,z4,z4};
  {
    const float* fwp = few + (size_t)(ebase + wv*16 + ln)*128;
    const short8* B = (const short8*)(wsb + FC1_OFF);
    #pragma unroll
    for (int c = 0; c < 4; c++){
      float4 fa  = *(const float4*)(fwp + c*32 + q8);
      float4 fbv = *(const float4*)(fwp + c*32 + q8 + 4);
      U8 a;
      a.u[0]=f2b2(fa.x,fa.y);   a.u[1]=f2b2(fa.z,fa.w);
      a.u[2]=f2b2(fbv.x,fbv.y); a.u[3]=f2b2(fbv.z,fbv.w);
      #pragma unroll
      for (int t = 0; t < 4; t++) accF[t] = mfma16(a.v, B[(c*4+t)*64 + lane], accF[t]);
    }
  }
  #pragma unroll
  for (int t = 0; t < 4; t++){
    float bb = fb1[(t<<4)+ln];
    #pragma unroll
    for (int r = 0; r < 4; r++)
      HB(wv, (quad<<2)+r, (t<<4)+ln) = f2b(silu_f(accF[t][r] + bb));
  }
  f32x4 acc2[4] = {z4,z4,z4,z4};
  {
    const short8* B = (const short8*)(wsb + FC2_OFF);
    #pragma unroll
    for (int c = 0; c < 2; c++){
      uint4 hq = *(const uint4*)&HB(wv, ln, c*32 + q8);
      U8 a; a.u[0]=hq.x; a.u[1]=hq.y; a.u[2]=hq.z; a.u[3]=hq.w;
      #pragma unroll
      for (int t = 0; t < 4; t++) acc2[t] = mfma16(a.v, B[(c*4+t)*64 + lane], acc2[t]);
    }
  }
  #pragma unroll
  for (int t = 0; t < 4; t++){
    float bb = fb2[(t<<4)+ln];
    #pragma unroll
    for (int r = 0; r < 4; r++)
      HB(wv, (quad<<2)+r, (t<<4)+ln) = f2b(silu_f(acc2[t][r] + bb));
  }
  f32x4 acc3[6] = {z4,z4,z4,z4,z4,z4};
  {
    const short8* B = (const short8*)(wsb + FC3_OFF);
    #pragma unroll
    for (int c = 0; c < 2; c++){
      uint4 hq = *(const uint4*)&HB(wv, ln, c*32 + q8);
      U8 a; a.u[0]=hq.x; a.u[1]=hq.y; a.u[2]=hq.z; a.u[3]=hq.w;
      #pragma unroll
      for (int t = 0; t < 6; t++) acc3[t] = mfma16(a.v, B[(c*6+t)*64 + lane], acc3[t]);
    }
  }

  // ---- epilogue ----
  #pragma unroll
  for (int r = 0; r < 4; r++){
    int eg = ebase + wv*16 + (quad<<2) + r;
    float* op = out + (size_t)eg*160;
    #pragma unroll
    for (int t = 0; t < 4; t++)
      op[(t<<4)+ln] = silu_f(P[t][r]) * (acc3[t][r] + fb3[(t<<4)+ln]);
    #pragma unroll
    for (int tp = 0; tp < 2; tp++){
      int wc = (tp<<4) + ln;
      float f = sigm_f(P[4+tp][r]) * (acc3[4+tp][r] + fb3[64+wc]);
      op[64 + wc*3 + 0] = P[6+3*tp+0][r] * f;
      op[64 + wc*3 + 1] = P[6+3*tp+1][r] * f;
      op[64 + wc*3 + 2] = P[6+3*tp+2][r] * f;
    }
  }
}

extern "C" void kernel_launch(void* const* d_in, const int* in_sizes, int n_in,
                              void* d_out, int out_size, void* d_ws, size_t ws_size,
                              hipStream_t stream) {
  (void)in_sizes; (void)n_in; (void)out_size; (void)ws_size;
  unsigned short* wsb = (unsigned short*)d_ws;

  prep_weights<<<(WS_USH/8 + 255)/256, 256, 0, stream>>>(
      (const float*)d_in[3], (const float*)d_in[5],     // ss_s, ss_g
      (const float*)d_in[4], (const float*)d_in[6],     // vv_s, vv_g
      (const float*)d_in[7], (const float*)d_in[8],     // sv, vs
      (const float*)d_in[9], (const float*)d_in[11], (const float*)d_in[13],
      wsb);

  equiconv_main<<<(E_TOT + 63)/64, 256, 0, stream>>>(
      (const float*)d_in[0], (const float*)d_in[1], (const float*)d_in[2],
      (const float*)d_in[10], (const float*)d_in[12], (const float*)d_in[14],
      (const unsigned short*)wsb, (float*)d_out);
}